// Round 6
// baseline (126.769 us; speedup 1.0000x reference)
//
#include <hip/hip_runtime.h>
#include <hip/hip_bf16.h>

#define GRP   8
#define PCH   64
#define FO    256
#define CIN   512
#define PTILE 16
#define XROW  520          // u16 per staged x row (512 + 8 pad)
#define TPB   7            // tiles per block
#define NTILE 1568         // 25088 / 16
#define NBLK  224          // NTILE / TPB

typedef __attribute__((ext_vector_type(8))) short bf16x8;
typedef __attribute__((ext_vector_type(4))) float f32x4;

__device__ __forceinline__ short f2b(float f) {
    __hip_bfloat16 h = __float2bfloat16(f);
    short s;
    __builtin_memcpy(&s, &h, 2);
    return s;
}
__device__ __forceinline__ float sigmoidf_(float b) {
    return 1.0f / (1.0f + __expf(-b));
}
__device__ __forceinline__ float dot4(f32x4 a, f32x4 b) {
    return fmaf(a[0], b[0], fmaf(a[1], b[1], fmaf(a[2], b[2], a[3] * b[3])));
}
// upper-tri (with diagonal) index for 8x8, i<=j
__device__ __forceinline__ constexpr int TRI(int i, int j) {
    int a = i < j ? i : j, b = i < j ? j : i;
    return a * 8 - a * (a - 1) / 2 + (b - a);
}

// ---- pre-kernel: repack kernels fp32 [g][p][f] -> bf16 MFMA A-frag order ----
// wpk[(((g*16+t)*2+kb)*64+lane)*8+j] = w[g][ p=kb*32+(lane>>4)*8+j ][ f=t*16+(lane&15) ]
__global__ void repack_w(const float* __restrict__ wk, unsigned short* __restrict__ wpk) {
    int id = blockIdx.x * 256 + threadIdx.x;      // 0 .. 131071
    int j    = id & 7;
    int lane = (id >> 3) & 63;
    int kb   = (id >> 9) & 1;
    int t    = (id >> 10) & 15;
    int g    = id >> 14;
    int p = kb * 32 + (lane >> 4) * 8 + j;
    int f = t * 16 + (lane & 15);
    unsigned short u;
    __hip_bfloat16 h = __float2bfloat16(wk[(g * PCH + p) * FO + f]);
    __builtin_memcpy(&u, &h, 2);
    wpk[id] = u;
}

__global__ __launch_bounds__(1024, 1)
void dynroute_pers(const float* __restrict__ x, const unsigned short* __restrict__ wpk,
                   const float* __restrict__ bias, float* __restrict__ out) {
    __shared__ unsigned short xs[2][PTILE * XROW];   // 32.5 KB double-buffered bf16 x
    __shared__ float part_s[16 * PTILE * 36];        // [wave][pos][pair], 36 KB
    __shared__ float Gs[PTILE * 36];                 // reduced Gram, 2.25 KB
    __shared__ float alpha_s[PTILE][8];

    const int tid  = threadIdx.x;
    const int lane = tid & 63;
    const int wave = tid >> 6;                // 0..15 == f-tile t
    const int pos  = lane & 15;
    const int lq   = lane >> 4;               // 0..3

    const int t0 = blockIdx.x * TPB;

    // bias for this lane's f-quad (resident)
    const float4 bb = *reinterpret_cast<const float4*>(bias + wave * 16 + lq * 4);

    // ---- prologue: stage tile t0 into xs[0]; prefetch tile t0+1 into regs ----
    {
        const float* p = x + ((size_t)(t0 * PTILE + wave)) * CIN + lane * 8;
        const float4 r0 = *reinterpret_cast<const float4*>(p);
        const float4 r1 = *reinterpret_cast<const float4*>(p + 4);
        bf16x8 v;
        v[0] = f2b(r0.x); v[1] = f2b(r0.y); v[2] = f2b(r0.z); v[3] = f2b(r0.w);
        v[4] = f2b(r1.x); v[5] = f2b(r1.y); v[6] = f2b(r1.z); v[7] = f2b(r1.w);
        *reinterpret_cast<bf16x8*>(&xs[0][wave * XROW + lane * 8]) = v;
    }
    float4 ra, rb;
    {
        const float* p = x + ((size_t)((t0 + 1) * PTILE + wave)) * CIN + lane * 8;
        ra = *reinterpret_cast<const float4*>(p);
        rb = *reinterpret_cast<const float4*>(p + 4);
    }
    __syncthreads();

    for (int i = 0; i < TPB; ++i) {
        const int buf  = i & 1;
        const int tile = t0 + i;

        // ---------------- MFMA: con for this tile, in VGPRs ----------------
        f32x4 acc[GRP];
        {
            const unsigned short* xrow = &xs[buf][pos * XROW];
            #pragma unroll
            for (int g = 0; g < GRP; ++g) {
                const bf16x8 xf0 = *reinterpret_cast<const bf16x8*>(&xrow[g * 64 + lq * 8]);
                const bf16x8 xf1 = *reinterpret_cast<const bf16x8*>(&xrow[g * 64 + 32 + lq * 8]);
                const bf16x8 wf0 = *reinterpret_cast<const bf16x8*>(
                    wpk + ((((g * 16 + wave) * 2 + 0) * 64 + lane) << 3));
                const bf16x8 wf1 = *reinterpret_cast<const bf16x8*>(
                    wpk + ((((g * 16 + wave) * 2 + 1) * 64 + lane) << 3));
                f32x4 a = {0.f, 0.f, 0.f, 0.f};
                a = __builtin_amdgcn_mfma_f32_16x16x32_bf16(wf0, xf0, a, 0, 0, 0);
                a = __builtin_amdgcn_mfma_f32_16x16x32_bf16(wf1, xf1, a, 0, 0, 0);
                acc[g] = a;   // con[pos][f = wave*16 + lq*4 + r]
            }
        }

        // ------- stage next tile (cvt+write), then prefetch tile i+2 -------
        {
            bf16x8 v;
            v[0] = f2b(ra.x); v[1] = f2b(ra.y); v[2] = f2b(ra.z); v[3] = f2b(ra.w);
            v[4] = f2b(rb.x); v[5] = f2b(rb.y); v[6] = f2b(rb.z); v[7] = f2b(rb.w);
            *reinterpret_cast<bf16x8*>(&xs[buf ^ 1][wave * XROW + lane * 8]) = v;
            int tn = tile + 2;
            if (tn > NTILE - 1) tn = NTILE - 1;
            const float* p = x + ((size_t)(tn * PTILE + wave)) * CIN + lane * 8;
            ra = *reinterpret_cast<const float4*>(p);
            rb = *reinterpret_cast<const float4*>(p + 4);
        }

        // ---------------- Gram partials: 36 pair dots ----------------------
        float pg[36];
        {
            int idx = 0;
            #pragma unroll
            for (int gi = 0; gi < GRP; ++gi)
                #pragma unroll
                for (int gj = gi; gj < GRP; ++gj)
                    pg[idx++] = dot4(acc[gi], acc[gj]);
        }
        #pragma unroll
        for (int j = 0; j < 36; ++j) {
            pg[j] += __shfl_xor(pg[j], 16, 64);
            pg[j] += __shfl_xor(pg[j], 32, 64);
        }
        if (lq == 0) {
            float* dst = &part_s[(wave * PTILE + pos) * 36];
            #pragma unroll
            for (int j4 = 0; j4 < 9; ++j4) {
                float4 w4 = {pg[4 * j4], pg[4 * j4 + 1], pg[4 * j4 + 2], pg[4 * j4 + 3]};
                *reinterpret_cast<float4*>(dst + 4 * j4) = w4;
            }
        }
        __syncthreads();   // B1

        // ---------------- reduce Gram over 16 waves ------------------------
        if (tid < 576) {                       // waves 0..8, no intra-wave divergence
            const int pp = tid / 36;
            const int j  = tid - pp * 36;
            float s0 = 0.f, s1 = 0.f, s2 = 0.f, s3 = 0.f;
            #pragma unroll
            for (int w = 0; w < 16; w += 4) {
                s0 += part_s[((w + 0) * PTILE + pp) * 36 + j];
                s1 += part_s[((w + 1) * PTILE + pp) * 36 + j];
                s2 += part_s[((w + 2) * PTILE + pp) * 36 + j];
                s3 += part_s[((w + 3) * PTILE + pp) * 36 + j];
            }
            Gs[pp * 36 + j] = (s0 + s1) + (s2 + s3);
        }
        __syncthreads();   // B2

        // ---------------- routing: 16 threads, one per position ------------
        if (tid < 16) {
            float g36[36];
            #pragma unroll
            for (int j = 0; j < 36; ++j) g36[j] = Gs[tid * 36 + j];
            float b1[8], a1[8];
            #pragma unroll
            for (int g = 0; g < 8; ++g) {
                float s = 0.f;
                #pragma unroll
                for (int g2 = 0; g2 < 8; ++g2) s += g36[TRI(g, g2)];
                b1[g] = 0.5f * s;
                a1[g] = sigmoidf_(b1[g]);
            }
            #pragma unroll
            for (int g = 0; g < 8; ++g) {
                float s = b1[g];
                #pragma unroll
                for (int g2 = 0; g2 < 8; ++g2) s = fmaf(g36[TRI(g, g2)], a1[g2], s);
                alpha_s[tid][g] = sigmoidf_(s);
            }
        }
        __syncthreads();   // B3

        // ---------------- epilogue: out = sum_g alpha2[g]*con_g + bias -----
        {
            const float4 A0 = *reinterpret_cast<const float4*>(&alpha_s[pos][0]);
            const float4 A1 = *reinterpret_cast<const float4*>(&alpha_s[pos][4]);
            const float av[8] = {A0.x, A0.y, A0.z, A0.w, A1.x, A1.y, A1.z, A1.w};
            f32x4 o = {bb.x, bb.y, bb.z, bb.w};
            #pragma unroll
            for (int g = 0; g < GRP; ++g) o = av[g] * acc[g] + o;
            *reinterpret_cast<float4*>(
                out + ((size_t)(tile * PTILE + pos)) * FO + wave * 16 + lq * 4) =
                *reinterpret_cast<float4*>(&o);
        }
    }
}

extern "C" void kernel_launch(void* const* d_in, const int* in_sizes, int n_in,
                              void* d_out, int out_size, void* d_ws, size_t ws_size,
                              hipStream_t stream) {
    const float* x    = (const float*)d_in[0];
    const float* wk   = (const float*)d_in[1];
    const float* bias = (const float*)d_in[2];
    float* out        = (float*)d_out;
    unsigned short* wpk = (unsigned short*)d_ws;   // 256 KB of workspace

    hipLaunchKernelGGL(repack_w, dim3(512), dim3(256), 0, stream, wk, wpk);
    hipLaunchKernelGGL(dynroute_pers, dim3(NBLK), dim3(1024), 0, stream,
                       x, wpk, bias, out);
}

// Round 7
// 87.965 us; speedup vs baseline: 1.4411x; 1.4411x over previous
//
#include <hip/hip_runtime.h>
#include <hip/hip_bf16.h>

#define GRP   8
#define PCH   64
#define FO    256
#define CIN   512
#define PTILE 16
#define XROW  520          // u16 per staged x row (512 + 8 pad)
#define NTILE 1568         // 25088 / 16
#define GRIDB 256          // persistent blocks, 1 per CU

typedef __attribute__((ext_vector_type(8))) short bf16x8;
typedef __attribute__((ext_vector_type(4))) float f32x4;

__device__ __forceinline__ short f2b(float f) {
    __hip_bfloat16 h = __float2bfloat16(f);
    short s;
    __builtin_memcpy(&s, &h, 2);
    return s;
}
__device__ __forceinline__ float sigmoidf_(float b) {
    return 1.0f / (1.0f + __expf(-b));
}
__device__ __forceinline__ float dot4(f32x4 a, f32x4 b) {
    return fmaf(a[0], b[0], fmaf(a[1], b[1], fmaf(a[2], b[2], a[3] * b[3])));
}

// ---- pre-kernel: repack kernels fp32 [g][p][f] -> bf16 MFMA A-frag order ----
// wpk[(((g*16+t)*2+kb)*64+lane)*8+j] = w[g][ p=kb*32+(lane>>4)*8+j ][ f=t*16+(lane&15) ]
__global__ void repack_w(const float* __restrict__ wk, unsigned short* __restrict__ wpk) {
    int id = blockIdx.x * 256 + threadIdx.x;      // 0 .. 131071
    int j    = id & 7;
    int lane = (id >> 3) & 63;
    int kb   = (id >> 9) & 1;
    int t    = (id >> 10) & 15;
    int g    = id >> 14;
    int p = kb * 32 + (lane >> 4) * 8 + j;
    int f = t * 16 + (lane & 15);
    unsigned short u;
    __hip_bfloat16 h = __float2bfloat16(wk[(g * PCH + p) * FO + f]);
    __builtin_memcpy(&u, &h, 2);
    wpk[id] = u;
}

__global__ __launch_bounds__(1024, 1)
void dynroute_pers(const float* __restrict__ x, const unsigned short* __restrict__ wpk,
                   const float* __restrict__ bias, float* __restrict__ out) {
    __shared__ unsigned short xs[2][PTILE * XROW];   // 32.5 KB double-buffered bf16 x
    __shared__ float part_s[16][PTILE][8];           // [wave][pos][g], 8 KB
    __shared__ float alpha1_s[PTILE][8];
    __shared__ float alpha2_s[PTILE][8];

    const int tid  = threadIdx.x;
    const int lane = tid & 63;
    const int wave = tid >> 6;                // 0..15 == f-tile t
    const int pos  = lane & 15;
    const int lq   = lane >> 4;               // 0..3
    const int bid  = blockIdx.x;
    const int niter = (bid < NTILE - 6 * GRIDB) ? 7 : 6;   // 32 blocks do 7 tiles

    const float4 bb = *reinterpret_cast<const float4*>(bias + wave * 16 + lq * 4);

    // ---- prologue: stage tile bid into xs[0]; prefetch tile bid+GRIDB ------
    {
        const float* p = x + ((size_t)(bid * PTILE + wave)) * CIN + lane * 8;
        const float4 r0 = *reinterpret_cast<const float4*>(p);
        const float4 r1 = *reinterpret_cast<const float4*>(p + 4);
        bf16x8 v;
        v[0] = f2b(r0.x); v[1] = f2b(r0.y); v[2] = f2b(r0.z); v[3] = f2b(r0.w);
        v[4] = f2b(r1.x); v[5] = f2b(r1.y); v[6] = f2b(r1.z); v[7] = f2b(r1.w);
        *reinterpret_cast<bf16x8*>(&xs[0][wave * XROW + lane * 8]) = v;
    }
    float4 ra, rb;
    {
        int tn = bid + GRIDB;
        if (tn >= NTILE) tn = bid;
        const float* p = x + ((size_t)(tn * PTILE + wave)) * CIN + lane * 8;
        ra = *reinterpret_cast<const float4*>(p);
        rb = *reinterpret_cast<const float4*>(p + 4);
    }
    __syncthreads();

    for (int i = 0; i < niter; ++i) {
        const int tile = bid + i * GRIDB;
        const int buf  = i & 1;

        // ---------------- MFMA: con for this tile, in VGPRs ----------------
        f32x4 acc[GRP];
        {
            const unsigned short* xrow = &xs[buf][pos * XROW];
            #pragma unroll
            for (int g = 0; g < GRP; ++g) {
                const bf16x8 xf0 = *reinterpret_cast<const bf16x8*>(&xrow[g * 64 + lq * 8]);
                const bf16x8 xf1 = *reinterpret_cast<const bf16x8*>(&xrow[g * 64 + 32 + lq * 8]);
                const bf16x8 wf0 = *reinterpret_cast<const bf16x8*>(
                    wpk + ((((g * 16 + wave) * 2 + 0) * 64 + lane) << 3));
                const bf16x8 wf1 = *reinterpret_cast<const bf16x8*>(
                    wpk + ((((g * 16 + wave) * 2 + 1) * 64 + lane) << 3));
                f32x4 a = {0.f, 0.f, 0.f, 0.f};
                a = __builtin_amdgcn_mfma_f32_16x16x32_bf16(wf0, xf0, a, 0, 0, 0);
                a = __builtin_amdgcn_mfma_f32_16x16x32_bf16(wf1, xf1, a, 0, 0, 0);
                acc[g] = a;   // con[pos][f = wave*16 + lq*4 + r]
            }
        }

        // ------- stage next tile (cvt+write), then prefetch tile i+2 -------
        {
            bf16x8 v;
            v[0] = f2b(ra.x); v[1] = f2b(ra.y); v[2] = f2b(ra.z); v[3] = f2b(ra.w);
            v[4] = f2b(rb.x); v[5] = f2b(rb.y); v[6] = f2b(rb.z); v[7] = f2b(rb.w);
            *reinterpret_cast<bf16x8*>(&xs[buf ^ 1][wave * XROW + lane * 8]) = v;
            int tn = tile + 2 * GRIDB;
            if (tn >= NTILE) tn = tile;
            const float* p = x + ((size_t)(tn * PTILE + wave)) * CIN + lane * 8;
            ra = *reinterpret_cast<const float4*>(p);
            rb = *reinterpret_cast<const float4*>(p + 4);
        }

        // ---------------- routing round 1: d1 = <con_g, S> -----------------
        f32x4 s0 = acc[0];
        #pragma unroll
        for (int g = 1; g < GRP; ++g) s0 += acc[g];

        float d1[GRP];
        #pragma unroll
        for (int g = 0; g < GRP; ++g) d1[g] = dot4(acc[g], s0);
        #pragma unroll
        for (int g = 0; g < GRP; ++g) {
            d1[g] += __shfl_xor(d1[g], 16, 64);
            d1[g] += __shfl_xor(d1[g], 32, 64);
        }
        if (lq == 0) {
            float4 v0 = {d1[0], d1[1], d1[2], d1[3]};
            float4 v1 = {d1[4], d1[5], d1[6], d1[7]};
            *reinterpret_cast<float4*>(&part_s[wave][pos][0]) = v0;
            *reinterpret_cast<float4*>(&part_s[wave][pos][4]) = v1;
        }
        __syncthreads();   // B1

        float b1r = 0.f;
        if (tid < 128) {       // thread handles (pos = tid>>3, g = tid&7)
            const int rp = tid >> 3, rg = tid & 7;
            float s = 0.f;
            #pragma unroll
            for (int w = 0; w < 16; ++w) s += part_s[w][rp][rg];
            b1r = 0.5f * s;
            alpha1_s[rp][rg] = sigmoidf_(b1r);
        }
        __syncthreads();   // B2

        // ---------------- routing round 2: d2 = <con_g, S_alpha> -----------
        float a1v[GRP];
        #pragma unroll
        for (int g = 0; g < GRP; ++g) a1v[g] = alpha1_s[pos][g];
        f32x4 sa0 = acc[0] * a1v[0];
        #pragma unroll
        for (int g = 1; g < GRP; ++g) sa0 = a1v[g] * acc[g] + sa0;

        float d2[GRP];
        #pragma unroll
        for (int g = 0; g < GRP; ++g) d2[g] = dot4(acc[g], sa0);
        #pragma unroll
        for (int g = 0; g < GRP; ++g) {
            d2[g] += __shfl_xor(d2[g], 16, 64);
            d2[g] += __shfl_xor(d2[g], 32, 64);
        }
        if (lq == 0) {
            float4 v0 = {d2[0], d2[1], d2[2], d2[3]};
            float4 v1 = {d2[4], d2[5], d2[6], d2[7]};
            *reinterpret_cast<float4*>(&part_s[wave][pos][0]) = v0;
            *reinterpret_cast<float4*>(&part_s[wave][pos][4]) = v1;
        }
        __syncthreads();   // B3

        if (tid < 128) {
            const int rp = tid >> 3, rg = tid & 7;
            float s = 0.f;
            #pragma unroll
            for (int w = 0; w < 16; ++w) s += part_s[w][rp][rg];
            alpha2_s[rp][rg] = sigmoidf_(b1r + s);
        }
        __syncthreads();   // B4

        // ---------------- epilogue: out = sum_g alpha2[g]*con_g + bias -----
        {
            const float4 A0 = *reinterpret_cast<const float4*>(&alpha2_s[pos][0]);
            const float4 A1 = *reinterpret_cast<const float4*>(&alpha2_s[pos][4]);
            const float av[8] = {A0.x, A0.y, A0.z, A0.w, A1.x, A1.y, A1.z, A1.w};
            f32x4 o = {bb.x, bb.y, bb.z, bb.w};
            #pragma unroll
            for (int g = 0; g < GRP; ++g) o = av[g] * acc[g] + o;
            *reinterpret_cast<float4*>(
                out + ((size_t)(tile * PTILE + pos)) * FO + wave * 16 + lq * 4) =
                *reinterpret_cast<float4*>(&o);
        }
    }
}

extern "C" void kernel_launch(void* const* d_in, const int* in_sizes, int n_in,
                              void* d_out, int out_size, void* d_ws, size_t ws_size,
                              hipStream_t stream) {
    const float* x    = (const float*)d_in[0];
    const float* wk   = (const float*)d_in[1];
    const float* bias = (const float*)d_in[2];
    float* out        = (float*)d_out;
    unsigned short* wpk = (unsigned short*)d_ws;   // 256 KB of workspace

    hipLaunchKernelGGL(repack_w, dim3(512), dim3(256), 0, stream, wk, wpk);
    hipLaunchKernelGGL(dynroute_pers, dim3(GRIDB), dim3(1024), 0, stream,
                       x, wpk, bias, out);
}

// Round 8
// 55.093 us; speedup vs baseline: 2.3010x; 1.5967x over previous
//
#include <hip/hip_runtime.h>

#define GRP   8
#define FO    256
#define CIN   512
#define PTILE 16
#define XROW  520          // u16 per staged x row (512 + 8 pad)
#define NTILE 1568         // 25088 / 16

typedef __attribute__((ext_vector_type(8))) short bf16x8;
typedef __attribute__((ext_vector_type(4))) float f32x4;

__device__ __forceinline__ unsigned f2bu(float f) {
    unsigned u = __float_as_uint(f);
    return (u + 0x7FFFu + ((u >> 16) & 1u)) >> 16;   // RNE to bf16 (validated R1)
}
__device__ __forceinline__ short f2b(float f) { return (short)f2bu(f); }
__device__ __forceinline__ unsigned pk2(float a, float b) {
    return f2bu(a) | (f2bu(b) << 16);
}
__device__ __forceinline__ float ulo(unsigned u) { return __uint_as_float(u << 16); }
__device__ __forceinline__ float uhi(unsigned u) { return __uint_as_float(u & 0xffff0000u); }
__device__ __forceinline__ float sigmoidf_(float b) {
    return 1.0f / (1.0f + __expf(-b));
}

// ---- pre-kernel: repack kernels fp32 [g][p][f] -> bf16 MFMA A-frag order ----
// wpk[(((g*16+t)*2+kb)*64+lane)*8+j] = w[g][ p=kb*32+(lane>>4)*8+j ][ f=t*16+(lane&15) ]
__global__ void repack_w(const float* __restrict__ wk, unsigned short* __restrict__ wpk) {
    int id = blockIdx.x * 256 + threadIdx.x;      // 0 .. 131071
    int j    = id & 7;
    int lane = (id >> 3) & 63;
    int kb   = (id >> 9) & 1;
    int t    = (id >> 10) & 15;
    int g    = id >> 14;
    int p = kb * 32 + (lane >> 4) * 8 + j;
    int f = t * 16 + (lane & 15);
    wpk[id] = (unsigned short)f2bu(wk[(g * 64 + p) * FO + f]);
}

__global__ __launch_bounds__(512, 1)
void dynroute_pk(const float* __restrict__ x, const unsigned short* __restrict__ wpk,
                 const float* __restrict__ bias, float* __restrict__ out) {
    __shared__ unsigned short xs[PTILE * XROW];   // 16.25 KB bf16 x tile
    __shared__ float part_s[8][PTILE][8];         // [wave][pos][g], 4 KB
    __shared__ float alpha1_s[PTILE][8];
    __shared__ float alpha2_s[PTILE][8];

    const int tid  = threadIdx.x;
    const int lane = tid & 63;
    const int wave = tid >> 6;                // 0..7, owns f-tiles wave*2 + {0,1}
    const int pos  = lane & 15;
    const int lq   = lane >> 4;               // 0..3
    const long m0  = (long)blockIdx.x * PTILE;

    // ---------------- stage x tile -> LDS as bf16 --------------------------
    {
        const int row = tid >> 5;             // 0..15 (32 threads per row)
        const int c0  = (tid & 31) * 16;      // f32 col, 16 per thread
        const float* p = x + (m0 + row) * CIN + c0;
        const float4 u0 = *reinterpret_cast<const float4*>(p);
        const float4 u1 = *reinterpret_cast<const float4*>(p + 4);
        const float4 u2 = *reinterpret_cast<const float4*>(p + 8);
        const float4 u3 = *reinterpret_cast<const float4*>(p + 12);
        bf16x8 v0, v1;
        v0[0] = f2b(u0.x); v0[1] = f2b(u0.y); v0[2] = f2b(u0.z); v0[3] = f2b(u0.w);
        v0[4] = f2b(u1.x); v0[5] = f2b(u1.y); v0[6] = f2b(u1.z); v0[7] = f2b(u1.w);
        v1[0] = f2b(u2.x); v1[1] = f2b(u2.y); v1[2] = f2b(u2.z); v1[3] = f2b(u2.w);
        v1[4] = f2b(u3.x); v1[5] = f2b(u3.y); v1[6] = f2b(u3.z); v1[7] = f2b(u3.w);
        *reinterpret_cast<bf16x8*>(&xs[row * XROW + c0]) = v0;
        *reinterpret_cast<bf16x8*>(&xs[row * XROW + c0 + 8]) = v1;
    }
    __syncthreads();

    // ---------------- MFMA: con (bf16-packed in regs) + running S ----------
    // con[tt][g]: lane holds f = (wave*2+tt)*16 + lq*4 + {0..3} for position pos
    unsigned cl[2][GRP], ch[2][GRP];
    f32x4 S0 = {0.f, 0.f, 0.f, 0.f}, S1 = {0.f, 0.f, 0.f, 0.f};
    {
        const unsigned short* xrow = &xs[pos * XROW];
        const unsigned short* wb = wpk + wave * 2048 + lane * 8;
        #pragma unroll
        for (int g = 0; g < GRP; ++g) {
            const bf16x8 xf0 = *reinterpret_cast<const bf16x8*>(&xrow[g * 64 + lq * 8]);
            const bf16x8 xf1 = *reinterpret_cast<const bf16x8*>(&xrow[g * 64 + 32 + lq * 8]);
            #pragma unroll
            for (int tt = 0; tt < 2; ++tt) {
                const bf16x8 wf0 = *reinterpret_cast<const bf16x8*>(
                    wb + g * 16384 + tt * 1024);
                const bf16x8 wf1 = *reinterpret_cast<const bf16x8*>(
                    wb + g * 16384 + tt * 1024 + 512);
                f32x4 a = {0.f, 0.f, 0.f, 0.f};
                a = __builtin_amdgcn_mfma_f32_16x16x32_bf16(wf0, xf0, a, 0, 0, 0);
                a = __builtin_amdgcn_mfma_f32_16x16x32_bf16(wf1, xf1, a, 0, 0, 0);
                if (tt == 0) S0 += a; else S1 += a;
                cl[tt][g] = pk2(a[0], a[1]);
                ch[tt][g] = pk2(a[2], a[3]);
            }
        }
    }

    // ---------------- routing round 1: d1[g] = <con_g, S> ------------------
    float d1[GRP];
    #pragma unroll
    for (int g = 0; g < GRP; ++g) {
        float s =      ulo(cl[0][g]) * S0[0];
        s = fmaf(uhi(cl[0][g]), S0[1], s);
        s = fmaf(ulo(ch[0][g]), S0[2], s);
        s = fmaf(uhi(ch[0][g]), S0[3], s);
        s = fmaf(ulo(cl[1][g]), S1[0], s);
        s = fmaf(uhi(cl[1][g]), S1[1], s);
        s = fmaf(ulo(ch[1][g]), S1[2], s);
        s = fmaf(uhi(ch[1][g]), S1[3], s);
        d1[g] = s;
    }
    #pragma unroll
    for (int g = 0; g < GRP; ++g) {
        d1[g] += __shfl_xor(d1[g], 16, 64);
        d1[g] += __shfl_xor(d1[g], 32, 64);
    }
    if (lq == 0) {
        float4 v0 = {d1[0], d1[1], d1[2], d1[3]};
        float4 v1 = {d1[4], d1[5], d1[6], d1[7]};
        *reinterpret_cast<float4*>(&part_s[wave][pos][0]) = v0;
        *reinterpret_cast<float4*>(&part_s[wave][pos][4]) = v1;
    }
    __syncthreads();   // B1

    float b1r = 0.f;
    if (tid < 128) {       // thread handles (pos = tid>>3, g = tid&7)
        const int rp = tid >> 3, rg = tid & 7;
        float s = 0.f;
        #pragma unroll
        for (int w = 0; w < 8; ++w) s += part_s[w][rp][rg];
        b1r = 0.5f * s;
        alpha1_s[rp][rg] = sigmoidf_(b1r);
    }
    __syncthreads();   // B2

    // ---------------- routing round 2: d2[g] = <con_g, S_alpha> ------------
    float a1v[GRP];
    #pragma unroll
    for (int g = 0; g < GRP; ++g) a1v[g] = alpha1_s[pos][g];
    f32x4 sa0 = {0.f, 0.f, 0.f, 0.f}, sa1 = {0.f, 0.f, 0.f, 0.f};
    #pragma unroll
    for (int g = 0; g < GRP; ++g) {
        sa0[0] = fmaf(a1v[g], ulo(cl[0][g]), sa0[0]);
        sa0[1] = fmaf(a1v[g], uhi(cl[0][g]), sa0[1]);
        sa0[2] = fmaf(a1v[g], ulo(ch[0][g]), sa0[2]);
        sa0[3] = fmaf(a1v[g], uhi(ch[0][g]), sa0[3]);
        sa1[0] = fmaf(a1v[g], ulo(cl[1][g]), sa1[0]);
        sa1[1] = fmaf(a1v[g], uhi(cl[1][g]), sa1[1]);
        sa1[2] = fmaf(a1v[g], ulo(ch[1][g]), sa1[2]);
        sa1[3] = fmaf(a1v[g], uhi(ch[1][g]), sa1[3]);
    }
    float d2[GRP];
    #pragma unroll
    for (int g = 0; g < GRP; ++g) {
        float s =      ulo(cl[0][g]) * sa0[0];
        s = fmaf(uhi(cl[0][g]), sa0[1], s);
        s = fmaf(ulo(ch[0][g]), sa0[2], s);
        s = fmaf(uhi(ch[0][g]), sa0[3], s);
        s = fmaf(ulo(cl[1][g]), sa1[0], s);
        s = fmaf(uhi(cl[1][g]), sa1[1], s);
        s = fmaf(ulo(ch[1][g]), sa1[2], s);
        s = fmaf(uhi(ch[1][g]), sa1[3], s);
        d2[g] = s;
    }
    #pragma unroll
    for (int g = 0; g < GRP; ++g) {
        d2[g] += __shfl_xor(d2[g], 16, 64);
        d2[g] += __shfl_xor(d2[g], 32, 64);
    }
    if (lq == 0) {
        float4 v0 = {d2[0], d2[1], d2[2], d2[3]};
        float4 v1 = {d2[4], d2[5], d2[6], d2[7]};
        *reinterpret_cast<float4*>(&part_s[wave][pos][0]) = v0;
        *reinterpret_cast<float4*>(&part_s[wave][pos][4]) = v1;
    }
    __syncthreads();   // B3

    if (tid < 128) {
        const int rp = tid >> 3, rg = tid & 7;
        float s = 0.f;
        #pragma unroll
        for (int w = 0; w < 8; ++w) s += part_s[w][rp][rg];
        alpha2_s[rp][rg] = sigmoidf_(b1r + s);
    }
    __syncthreads();   // B4

    // ---------------- epilogue: out = sum_g alpha2[g]*con_g + bias ---------
    float a2v[GRP];
    #pragma unroll
    for (int g = 0; g < GRP; ++g) a2v[g] = alpha2_s[pos][g];
    const float4 bb0 = *reinterpret_cast<const float4*>(bias + (wave * 2 + 0) * 16 + lq * 4);
    const float4 bb1 = *reinterpret_cast<const float4*>(bias + (wave * 2 + 1) * 16 + lq * 4);
    f32x4 o0 = {bb0.x, bb0.y, bb0.z, bb0.w};
    f32x4 o1 = {bb1.x, bb1.y, bb1.z, bb1.w};
    #pragma unroll
    for (int g = 0; g < GRP; ++g) {
        o0[0] = fmaf(a2v[g], ulo(cl[0][g]), o0[0]);
        o0[1] = fmaf(a2v[g], uhi(cl[0][g]), o0[1]);
        o0[2] = fmaf(a2v[g], ulo(ch[0][g]), o0[2]);
        o0[3] = fmaf(a2v[g], uhi(ch[0][g]), o0[3]);
        o1[0] = fmaf(a2v[g], ulo(cl[1][g]), o1[0]);
        o1[1] = fmaf(a2v[g], uhi(cl[1][g]), o1[1]);
        o1[2] = fmaf(a2v[g], ulo(ch[1][g]), o1[2]);
        o1[3] = fmaf(a2v[g], uhi(ch[1][g]), o1[3]);
    }
    float* ob = out + (m0 + pos) * FO + lq * 4;
    *reinterpret_cast<float4*>(ob + (wave * 2 + 0) * 16) = *reinterpret_cast<float4*>(&o0);
    *reinterpret_cast<float4*>(ob + (wave * 2 + 1) * 16) = *reinterpret_cast<float4*>(&o1);
}

extern "C" void kernel_launch(void* const* d_in, const int* in_sizes, int n_in,
                              void* d_out, int out_size, void* d_ws, size_t ws_size,
                              hipStream_t stream) {
    const float* x    = (const float*)d_in[0];
    const float* wk   = (const float*)d_in[1];
    const float* bias = (const float*)d_in[2];
    float* out        = (float*)d_out;
    unsigned short* wpk = (unsigned short*)d_ws;   // 256 KB of workspace

    hipLaunchKernelGGL(repack_w, dim3(512), dim3(256), 0, stream, wk, wpk);
    hipLaunchKernelGGL(dynroute_pk, dim3(NTILE), dim3(512), 0, stream,
                       x, wpk, bias, out);
}